// Round 2
// baseline (599.504 us; speedup 1.0000x reference)
//
#include <hip/hip_runtime.h>
#include <math.h>

#define BB 8
#define CC 256
#define HWP 4096            // H*W
#define NN 1024             // codebook size
#define DD 256              // embedding dim
#define ZQ_SIZE (BB * DD * HWP)

typedef float v16f __attribute__((ext_vector_type(16)));

// Kernel 1: wT[257][1024]: wT[c][n] = w[n][c]; row 256 = bias (folded as an
// extra K-step so the main loop needs no separate bias path).
__global__ __launch_bounds__(256) void transpose_w_kernel(
    const float* __restrict__ w, const float* __restrict__ bias,
    float* __restrict__ wT)
{
    if (blockIdx.x == 256) {
        for (int i = threadIdx.x; i < NN; i += 256)
            wT[(size_t)256 * NN + i] = bias[i];
        return;
    }
    __shared__ float t[32][33];
    const int bn = blockIdx.x & 31;   // n-tile (32 tiles of 32)
    const int bc = blockIdx.x >> 5;   // c-tile (8 tiles of 32)
    const int x = threadIdx.x & 31, y = threadIdx.x >> 5;  // y in 0..7
#pragma unroll
    for (int k = 0; k < 4; ++k)
        t[y + k * 8][x] = w[(size_t)(bn * 32 + y + k * 8) * CC + bc * 32 + x];
    __syncthreads();
#pragma unroll
    for (int k = 0; k < 4; ++k)
        wT[(size_t)(bc * 32 + y + k * 8) * NN + bn * 32 + x] = t[x][y + k * 8];
}

// Kernel 2: per block 64 pixels x 1024 codes. 4 waves; wave wv handles codes
// [wv*256, wv*256+256) in 8 chunks of 32. lane = pixel. w via uniform
// (scalar-path) loads, z via coalesced global loads. No LDS in the K-loop.
__global__ __launch_bounds__(256) void argmax_quant_main(
    const float* __restrict__ z,      // [B, C, H*W]
    const float* __restrict__ wT,     // [257, 1024]
    const float* __restrict__ embed,  // [N, D]
    float* __restrict__ out)          // [z_q | diff | ind]
{
    __shared__ __align__(16) float tile[64][257];  // epilogue transpose
    __shared__ float redv[256];
    __shared__ int   redi[256];
    __shared__ int   indsh[64];

    const int tid  = threadIdx.x;
    const int lane = tid & 63;
    const int wv   = __builtin_amdgcn_readfirstlane(tid >> 6);
    const int b    = blockIdx.x >> 6;
    const int p0   = (blockIdx.x & 63) << 6;

    const float* zbase = z + (size_t)b * CC * HWP + p0 + lane;

    float bestv = -INFINITY;
    int   besti = 0;

    for (int ch = 0; ch < 8; ++ch) {
        const int n0 = wv * 256 + ch * 32;
        const float* wrow = wT + n0;
        // preload row 0 of this chunk
        v16f wa = *(const v16f*)(wrow);
        v16f wb = *(const v16f*)(wrow + 16);
        const float* zp = zbase;
        float zv = *zp;
        float acc[32];
#pragma unroll
        for (int j = 0; j < 32; ++j) acc[j] = 0.f;

        for (int c = 0; c < 256; ++c) {
            const int zo = (c < 255) ? HWP : 0;   // uniform; avoids OOB at c=255
            const float zn = zp[zo];              // z prefetch (vmcnt domain)
#pragma unroll
            for (int j = 0; j < 16; ++j) acc[j]      = fmaf(wa[j], zv, acc[j]);
#pragma unroll
            for (int j = 0; j < 16; ++j) acc[16 + j] = fmaf(wb[j], zv, acc[16 + j]);
            // Pin the next w-load AFTER this iteration's FMAs so the forced
            // lgkmcnt(0) drain (SMEM is out-of-order) sits a full compute
            // iteration after issue.
            __builtin_amdgcn_sched_barrier(0);
            const float* wn = wrow + (size_t)(c + 1) * NN;  // c=255 -> bias row
            wa = *(const v16f*)(wn);
            wb = *(const v16f*)(wn + 16);
            zv = zn;
            zp += zo;
        }
        // wa/wb now hold row 256 = bias. Add + running argmax (ascending n,
        // strict > => lowest index wins ties).
#pragma unroll
        for (int j = 0; j < 32; ++j) {
            const float v = acc[j] + ((j < 16) ? wa[j] : wb[j - 16]);
            if (v > bestv) { bestv = v; besti = n0 + j; }
        }
    }

    // Cross-wave argmax reduce: 4 candidates per pixel.
    redv[lane * 4 + wv] = bestv;
    redi[lane * 4 + wv] = besti;
    __syncthreads();
    if (tid < 64) {
        const int p = tid;
        float bv = redv[p * 4];
        int   bi = redi[p * 4];
#pragma unroll
        for (int t = 1; t < 4; ++t) {
            const float v  = redv[p * 4 + t];
            const int   i2 = redi[p * 4 + t];
            if (v > bv) { bv = v; bi = i2; }   // waves ascend in n: > keeps lowest
        }
        indsh[p] = bi;
        out[ZQ_SIZE + 1 + b * HWP + p0 + p] = (float)bi;  // ind as exact float
    }
    if (blockIdx.x == 0 && tid == 0) out[ZQ_SIZE] = 0.0f;  // diff
    __syncthreads();

    // Gather epilogue (validated in R1): embed rows -> LDS (coalesced reads),
    // then [b,d,h,w] writes coalesced along pixels.
    {
        const int l = tid & 63, wq = tid >> 6;
        for (int it = 0; it < 16; ++it) {
            const int p   = it * 4 + wq;
            const int row = indsh[p];
            const float4 e = *(const float4*)(embed + (size_t)row * DD + l * 4);
            tile[p][l * 4 + 0] = e.x;
            tile[p][l * 4 + 1] = e.y;
            tile[p][l * 4 + 2] = e.z;
            tile[p][l * 4 + 3] = e.w;
        }
        __syncthreads();
        float* outz = out + (size_t)b * DD * HWP + p0;
        for (int dd = 0; dd < 64; ++dd) {
            const int d = dd * 4 + wq;
            outz[(size_t)d * HWP + l] = tile[l][d];
        }
    }
}

extern "C" void kernel_launch(void* const* d_in, const int* in_sizes, int n_in,
                              void* d_out, int out_size, void* d_ws, size_t ws_size,
                              hipStream_t stream) {
    const float* z     = (const float*)d_in[0];
    const float* w     = (const float*)d_in[1];
    const float* bias  = (const float*)d_in[2];
    const float* embed = (const float*)d_in[3];
    float* wT  = (float*)d_ws;                 // needs 257*1024*4 = 1.05 MB
    float* out = (float*)d_out;

    hipLaunchKernelGGL(transpose_w_kernel, dim3(257), dim3(256), 0, stream,
                       w, bias, wT);
    hipLaunchKernelGGL(argmax_quant_main, dim3(512), dim3(256), 0, stream,
                       z, wT, embed, out);
}

// Round 3
// 269.881 us; speedup vs baseline: 2.2214x; 2.2214x over previous
//
#include <hip/hip_runtime.h>
#include <math.h>

#define HWP 4096
#define CCH 256
#define NN  1024
#define DD  256
#define ZQ_SIZE (8 * DD * HWP)       // 8388608 floats = 33554432 B
#define NPIX 32768
#define MARGIN 5e-5f

typedef _Float16 h8 __attribute__((ext_vector_type(8)));
typedef float    f4 __attribute__((ext_vector_type(4)));

// ---------- K1: split w -> wh/wl fp16 [1024][256] ----------
__global__ __launch_bounds__(256) void split_w_k(
    const float* __restrict__ w, _Float16* __restrict__ wh, _Float16* __restrict__ wl)
{
    const int i = blockIdx.x * 256 + threadIdx.x;   // grid 1024 -> 262144 exact
    const float x = w[i];
    const _Float16 h = (_Float16)x;
    wh[i] = h;
    wl[i] = (_Float16)(x - (float)h);
}

// ---------- K2: z[b][c][p] fp32 -> zTh/zTl[pix][c] fp16 (transpose+split) ----------
__global__ __launch_bounds__(256) void split_zt_k(
    const float* __restrict__ z, _Float16* __restrict__ zTh, _Float16* __restrict__ zTl)
{
    __shared__ float t[64][68];                      // [c][px], row 272 B (16B-aligned)
    const int tid = threadIdx.x;
    const int pt  = blockIdx.x >> 2;                 // 512 pixel-tiles of 64
    const int ct  = blockIdx.x & 3;                  // 4 c-tiles of 64
    const int b   = pt >> 6;
    const int p0  = (pt & 63) << 6;
    const int c0  = ct << 6;
    const float* zb = z + ((size_t)b * CCH + c0) * HWP + p0;
    {
        const int px4 = tid & 15, cr = tid >> 4;
#pragma unroll
        for (int it = 0; it < 4; ++it) {
            const int c = it * 16 + cr;
            const float4 v = *(const float4*)(zb + (size_t)c * HWP + px4 * 4);
            *(float4*)&t[c][px4 * 4] = v;
        }
    }
    __syncthreads();
    {
        const int c8 = tid & 7, pxl = tid >> 3;      // 32 px per pass
#pragma unroll
        for (int it = 0; it < 2; ++it) {
            const int px = it * 32 + pxl;
            _Float16 hv[8], lv[8];
#pragma unroll
            for (int i = 0; i < 8; ++i) {
                const float x = t[c8 * 8 + i][px];
                const _Float16 h = (_Float16)x;
                hv[i] = h;
                lv[i] = (_Float16)(x - (float)h);
            }
            const size_t off = (size_t)(pt * 64 + px) * CCH + c0 + c8 * 8;
            *(h8*)(zTh + off) = *(const h8*)hv;
            *(h8*)(zTl + off) = *(const h8*)lv;
        }
    }
}

// ---------- K3: MFMA logits + per-pixel top2 ----------
// 256 blocks x 512 thr. Block: 128 px x 1024 codes. Wave (8): nchunk=wv&3,
// phalf=wv>>2; wave tile 64px x 64n per n-iter (4 iters -> 1024 codes).
// A (zT hi/lo) staged in LDS pair-padded (1040 B per 2 rows -> 2-way-free b128);
// B (w hi/lo) straight from global/L2. 3 products: ah*bh + ah*bl + al*bh.
__global__ __launch_bounds__(512, 2) void mfma_top2_k(
    const _Float16* __restrict__ zTh, const _Float16* __restrict__ zTl,
    const _Float16* __restrict__ wh,  const _Float16* __restrict__ wl,
    const float* __restrict__ bias,
    int* __restrict__ idx_out, float* __restrict__ gap_out)
{
    __shared__ __align__(16) char smem[139264];      // zh 66560 | zl 66560 | merge 6144
    float* s_best = (float*)(smem + 133120);         // [4][128]
    float* s_sec  = (float*)(smem + 133120 + 2048);
    int*   s_idx  = (int*)  (smem + 133120 + 4096);

    const int tid  = threadIdx.x;
    const int l    = tid & 63;
    const int wv   = tid >> 6;
    const int nchunk = wv & 3;
    const int phalf  = wv >> 2;
    const int pix0 = blockIdx.x * 128;
    const int c15 = l & 15, g = l >> 4;

    // Stage A: 128 rows x 256 fp16 (hi+lo), pairs of rows = 1024 B + 16 pad.
    for (int p = wv; p < 64; p += 8) {
        const char* gh = (const char*)zTh + (size_t)(pix0 + p * 2) * CCH * 2;
        const char* gl = (const char*)zTl + (size_t)(pix0 + p * 2) * CCH * 2;
        *(int4*)(smem + p * 1040 + l * 16)         = *(const int4*)(gh + l * 16);
        *(int4*)(smem + 66560 + p * 1040 + l * 16) = *(const int4*)(gl + l * 16);
    }
    __syncthreads();

    float best[16], sec[16]; int bidx[16];
#pragma unroll
    for (int s = 0; s < 16; ++s) { best[s] = -INFINITY; sec[s] = -INFINITY; bidx[s] = 0; }

    const int mrow0 = phalf * 64;

#pragma unroll 1
    for (int it4 = 0; it4 < 4; ++it4) {
        const int nbase = it4 * 256 + nchunk * 64;
        const _Float16* wh_b = wh + (size_t)nbase * CCH;
        const _Float16* wl_b = wl + (size_t)nbase * CCH;
        f4 acc[4][4];
#pragma unroll
        for (int mf = 0; mf < 4; ++mf)
#pragma unroll
            for (int nf = 0; nf < 4; ++nf) acc[mf][nf] = (f4)0.f;

#pragma unroll 2
        for (int ks = 0; ks < 8; ++ks) {
            const int k0 = ks * 32 + g * 8;
            h8 ah[4], al[4], bh[4], bl[4];
#pragma unroll
            for (int mf = 0; mf < 4; ++mf) {
                const int m = mrow0 + mf * 16 + c15;
                const int aoff = (m >> 1) * 1040 + (m & 1) * 512 + k0 * 2;
                ah[mf] = *(const h8*)(smem + aoff);
                al[mf] = *(const h8*)(smem + 66560 + aoff);
            }
#pragma unroll
            for (int nf = 0; nf < 4; ++nf) {
                const size_t boff = (size_t)(nf * 16 + c15) * CCH + k0;
                bh[nf] = *(const h8*)(wh_b + boff);
                bl[nf] = *(const h8*)(wl_b + boff);
            }
#pragma unroll
            for (int mf = 0; mf < 4; ++mf)
#pragma unroll
                for (int nf = 0; nf < 4; ++nf) {
                    acc[mf][nf] = __builtin_amdgcn_mfma_f32_16x16x32_f16(ah[mf], bh[nf], acc[mf][nf], 0, 0, 0);
                    acc[mf][nf] = __builtin_amdgcn_mfma_f32_16x16x32_f16(ah[mf], bl[nf], acc[mf][nf], 0, 0, 0);
                    acc[mf][nf] = __builtin_amdgcn_mfma_f32_16x16x32_f16(al[mf], bh[nf], acc[mf][nf], 0, 0, 0);
                }
        }
        // fold (+bias) into per-lane top2; ascending n => strict > keeps lowest idx
#pragma unroll
        for (int nf = 0; nf < 4; ++nf) {
            const int n_abs = nbase + nf * 16 + c15;
            const float bv = bias[n_abs];
#pragma unroll
            for (int mf = 0; mf < 4; ++mf)
#pragma unroll
                for (int r = 0; r < 4; ++r) {
                    const float v = acc[mf][nf][r] + bv;
                    const int s = mf * 4 + r;
                    if (v > best[s]) { sec[s] = best[s]; best[s] = v; bidx[s] = n_abs; }
                    else if (v > sec[s]) sec[s] = v;
                }
        }
    }

    // butterfly merge across the 16 col-lanes (lane bits 0..3)
#pragma unroll
    for (int d = 1; d < 16; d <<= 1) {
#pragma unroll
        for (int s = 0; s < 16; ++s) {
            const float ob = __shfl_xor(best[s], d, 64);
            const float os = __shfl_xor(sec[s], d, 64);
            const int   oi = __shfl_xor(bidx[s], d, 64);
            if (ob > best[s])       { sec[s] = fmaxf(best[s], os); best[s] = ob; bidx[s] = oi; }
            else if (ob == best[s]) { sec[s] = ob; bidx[s] = (oi < bidx[s]) ? oi : bidx[s]; }
            else                    { sec[s] = fmaxf(sec[s], ob); }
        }
    }
    // lane with c15==s publishes slot s
#pragma unroll
    for (int s = 0; s < 16; ++s) {
        if (c15 == s) {
            const int m = mrow0 + (s >> 2) * 16 + g * 4 + (s & 3);
            s_best[nchunk * 128 + m] = best[s];
            s_sec [nchunk * 128 + m] = sec[s];
            s_idx [nchunk * 128 + m] = bidx[s];
        }
    }
    __syncthreads();
    if (tid < 128) {
        const int m = tid;
        float b0 = s_best[m], s0 = s_sec[m]; int i0 = s_idx[m];
#pragma unroll
        for (int c = 1; c < 4; ++c) {
            const float ob = s_best[c * 128 + m], os = s_sec[c * 128 + m];
            const int   oi = s_idx[c * 128 + m];
            if (ob > b0)       { s0 = fmaxf(b0, os); b0 = ob; i0 = oi; }
            else if (ob == b0) { s0 = ob; i0 = (oi < i0) ? oi : i0; }
            else               { s0 = fmaxf(s0, ob); }
        }
        idx_out[pix0 + m] = i0;
        gap_out[pix0 + m] = b0 - s0;
    }
}

// ---------- K4: rare exact-fp32 fixup + gather epilogue ----------
__global__ __launch_bounds__(256) void finalize_k(
    const float* __restrict__ z, const float* __restrict__ w,
    const float* __restrict__ bias, const float* __restrict__ embed,
    const int* __restrict__ idx_in, const float* __restrict__ gap_in,
    float* __restrict__ out)
{
    __shared__ __align__(16) float tile[64][257];
    __shared__ int   indsh[64];
    __shared__ float gaps[64];
    __shared__ float redv[256];
    __shared__ int   redi[256];

    const int tid = threadIdx.x;
    const int blk = blockIdx.x;
    const int b = blk >> 6, p0 = (blk & 63) << 6;
    const int pix0 = blk * 64;

    if (tid < 64) { indsh[tid] = idx_in[pix0 + tid]; gaps[tid] = gap_in[pix0 + tid]; }
    __syncthreads();

    for (int px = 0; px < 64; ++px) {
        if (gaps[px] < MARGIN) {   // block-uniform branch; rare
            const float* zp = z + (size_t)b * CCH * HWP + p0 + px;
            const float* w0 = w + (size_t)tid * 4 * CCH;
            float a[4];
#pragma unroll
            for (int j = 0; j < 4; ++j) a[j] = bias[tid * 4 + j];
            for (int c = 0; c < CCH; ++c) {
                const float zv = zp[(size_t)c * HWP];
#pragma unroll
                for (int j = 0; j < 4; ++j) a[j] = fmaf(w0[j * CCH + c], zv, a[j]);
            }
            float bv = a[0]; int bi = tid * 4;
#pragma unroll
            for (int j = 1; j < 4; ++j)
                if (a[j] > bv) { bv = a[j]; bi = tid * 4 + j; }
            redv[tid] = bv; redi[tid] = bi;
            __syncthreads();
            if (tid < 64) {
                float v = redv[tid]; int i = redi[tid];
                for (int t2 = tid + 64; t2 < 256; t2 += 64) {
                    const float v2 = redv[t2]; const int i2 = redi[t2];
                    if (v2 > v || (v2 == v && i2 < i)) { v = v2; i = i2; }
                }
                redv[tid] = v; redi[tid] = i;
            }
            __syncthreads();
            if (tid == 0) {
                float v = redv[0]; int i = redi[0];
                for (int t2 = 1; t2 < 64; ++t2) {
                    const float v2 = redv[t2]; const int i2 = redi[t2];
                    if (v2 > v || (v2 == v && i2 < i)) { v = v2; i = i2; }
                }
                indsh[px] = i;
            }
            __syncthreads();
        }
    }

    if (tid < 64) out[ZQ_SIZE + 1 + pix0 + tid] = (float)indsh[tid];
    if (blk == 0 && tid == 0) out[ZQ_SIZE] = 0.0f;
    __syncthreads();

    // gather epilogue (validated in R1)
    {
        const int lq = tid & 63, wq = tid >> 6;
        for (int it = 0; it < 16; ++it) {
            const int p   = it * 4 + wq;
            const int row = indsh[p];
            const float4 e = *(const float4*)(embed + (size_t)row * DD + lq * 4);
            tile[p][lq * 4 + 0] = e.x;
            tile[p][lq * 4 + 1] = e.y;
            tile[p][lq * 4 + 2] = e.z;
            tile[p][lq * 4 + 3] = e.w;
        }
        __syncthreads();
        float* outz = out + (size_t)b * DD * HWP + p0;
        for (int dd = 0; dd < 64; ++dd) {
            const int d = dd * 4 + wq;
            outz[(size_t)d * HWP + lq] = tile[lq][d];
        }
    }
}

extern "C" void kernel_launch(void* const* d_in, const int* in_sizes, int n_in,
                              void* d_out, int out_size, void* d_ws, size_t ws_size,
                              hipStream_t stream) {
    const float* z     = (const float*)d_in[0];
    const float* w     = (const float*)d_in[1];
    const float* bias  = (const float*)d_in[2];
    const float* embed = (const float*)d_in[3];
    float* out = (float*)d_out;

    // ws layout: wh 512KB | wl 512KB | idx 128KB | gap 128KB  (1.25 MB)
    _Float16* wh = (_Float16*)d_ws;
    _Float16* wl = (_Float16*)((char*)d_ws + 524288);
    int*   idxb  = (int*)  ((char*)d_ws + 1048576);
    float* gapb  = (float*)((char*)d_ws + 1179648);

    // zT hi/lo live in d_out's z_q region (exactly 33554432 B); dead before
    // finalize_k overwrites it with z_q.
    _Float16* zTh = (_Float16*)d_out;
    _Float16* zTl = (_Float16*)d_out + ZQ_SIZE;     // fp16 elements: 8388608*2B = 16MB offset

    hipLaunchKernelGGL(split_w_k,   dim3(1024), dim3(256), 0, stream, w, wh, wl);
    hipLaunchKernelGGL(split_zt_k,  dim3(2048), dim3(256), 0, stream, z, zTh, zTl);
    hipLaunchKernelGGL(mfma_top2_k, dim3(256),  dim3(512), 0, stream,
                       zTh, zTl, wh, wl, bias, idxb, gapb);
    hipLaunchKernelGGL(finalize_k,  dim3(512),  dim3(256), 0, stream,
                       z, w, bias, embed, idxb, gapb, out);
}